// Round 11
// baseline (263.667 us; speedup 1.0000x reference)
//
#include <hip/hip_runtime.h>
#include <stdint.h>

#define NN 8192
#define FIN 1024
#define FOUT 512

typedef __attribute__((ext_vector_type(4))) float f32x4;
typedef __attribute__((ext_vector_type(8))) short s16x8;
typedef __attribute__((ext_vector_type(4))) unsigned short u16x4;

__device__ __forceinline__ short f2bf(float f) {
    return __builtin_bit_cast(short, static_cast<__bf16>(f));
}
__device__ __forceinline__ float bf2f(short s) {
    return (float)__builtin_bit_cast(__bf16, s);
}

// ---------- Kernel 1 (path A): fused prep ----------
// blocks [0,8192): rowsum+cvt adj->adjB ; [8192,12288): x->xB ; [12288,12416): W->WT
__global__ __launch_bounds__(256) void prep_kernel(const float* __restrict__ adj,
                                                   short* __restrict__ adjB,
                                                   float* __restrict__ d_is,
                                                   const float* __restrict__ x,
                                                   short* __restrict__ xB,
                                                   const float* __restrict__ W,
                                                   short* __restrict__ WT) {
    __shared__ float red[4];
    __shared__ float T[64][68];
    const int b = blockIdx.x;
    const int t = threadIdx.x;
    if (b < NN) {
        const int row = b;
        const float4* a = reinterpret_cast<const float4*>(adj + (size_t)row * NN);
        u16x4* ob = reinterpret_cast<u16x4*>(adjB + (size_t)row * NN);
        float s = 0.f;
        #pragma unroll 2
        for (int j = t; j < NN / 4; j += 256) {
            float4 v = a[j];
            s += (v.x + v.y) + (v.z + v.w);
            u16x4 p;
            p[0] = (unsigned short)f2bf(v.x); p[1] = (unsigned short)f2bf(v.y);
            p[2] = (unsigned short)f2bf(v.z); p[3] = (unsigned short)f2bf(v.w);
            ob[j] = p;
        }
        #pragma unroll
        for (int off = 32; off > 0; off >>= 1) s += __shfl_down(s, off, 64);
        if ((t & 63) == 0) red[t >> 6] = s;
        __syncthreads();
        if (t == 0) {
            const float d = red[0] + red[1] + red[2] + red[3] + 1.0f;
            d_is[row] = 1.0f / sqrtf(d);
        }
    } else if (b < NN + 4096) {
        const size_t i = ((size_t)(b - NN) * 256 + t) * 8;
        const float4 v0 = *reinterpret_cast<const float4*>(&x[i]);
        const float4 v1 = *reinterpret_cast<const float4*>(&x[i + 4]);
        s16x8 o;
        o[0] = f2bf(v0.x); o[1] = f2bf(v0.y); o[2] = f2bf(v0.z); o[3] = f2bf(v0.w);
        o[4] = f2bf(v1.x); o[5] = f2bf(v1.y); o[6] = f2bf(v1.z); o[7] = f2bf(v1.w);
        *reinterpret_cast<s16x8*>(&xB[i]) = o;
    } else {
        const int bid = b - NN - 4096;
        const int wc = bid & 7;
        const int wk = bid >> 3;
        const int cc = (t & 15) * 4;
        #pragma unroll
        for (int i = 0; i < 4; ++i) {
            const int rr = (t >> 4) + i * 16;
            *reinterpret_cast<float4*>(&T[rr][cc]) =
                *reinterpret_cast<const float4*>(&W[(size_t)(wk * 64 + rr) * FOUT + wc * 64 + cc]);
        }
        __syncthreads();
        const int a = t >> 2;
        const int b0 = (t & 3) * 16;
        s16x8 v0, v1;
        #pragma unroll
        for (int e = 0; e < 8; ++e) { v0[e] = f2bf(T[b0 + e][a]); v1[e] = f2bf(T[b0 + 8 + e][a]); }
        short* dst = &WT[(size_t)(wc * 64 + a) * FIN + wk * 64 + b0];
        *reinterpret_cast<s16x8*>(dst) = v0;
        *reinterpret_cast<s16x8*>(dst + 8) = v1;
    }
}

// ---------- Kernel 1B (fallback): rowsum only ----------
__global__ __launch_bounds__(256) void rowsum_kernel(const float* __restrict__ adj,
                                                     float* __restrict__ d_is) {
    const int row = blockIdx.x;
    const float4* a = reinterpret_cast<const float4*>(adj + (size_t)row * NN);
    float s = 0.f;
    #pragma unroll 4
    for (int j = threadIdx.x; j < NN / 4; j += 256) {
        float4 v = a[j];
        s += (v.x + v.y) + (v.z + v.w);
    }
    #pragma unroll
    for (int off = 32; off > 0; off >>= 1) s += __shfl_down(s, off, 64);
    __shared__ float red[4];
    if ((threadIdx.x & 63) == 0) red[threadIdx.x >> 6] = s;
    __syncthreads();
    if (threadIdx.x == 0) {
        const float d = red[0] + red[1] + red[2] + red[3] + 1.0f;
        d_is[row] = 1.0f / sqrtf(d);
    }
}

// ---------- Kernel wt (fallback) ----------
__global__ __launch_bounds__(256) void wt_kernel(const float* __restrict__ W,
                                                 short* __restrict__ WT) {
    __shared__ float T[64][68];
    const int wc = blockIdx.x;
    const int wk = blockIdx.y;
    const int t = threadIdx.x;
    const int cc = (t & 15) * 4;
    #pragma unroll
    for (int i = 0; i < 4; ++i) {
        const int rr = (t >> 4) + i * 16;
        *reinterpret_cast<float4*>(&T[rr][cc]) =
            *reinterpret_cast<const float4*>(&W[(size_t)(wk * 64 + rr) * FOUT + wc * 64 + cc]);
    }
    __syncthreads();
    const int a = t >> 2;
    const int b0 = (t & 3) * 16;
    s16x8 v0, v1;
    #pragma unroll
    for (int e = 0; e < 8; ++e) { v0[e] = f2bf(T[b0 + e][a]); v1[e] = f2bf(T[b0 + 8 + e][a]); }
    short* dst = &WT[(size_t)(wc * 64 + a) * FIN + wk * 64 + b0];
    *reinterpret_cast<s16x8*>(dst) = v0;
    *reinterpret_cast<s16x8*>(dst + 8) = v1;
}

// ---------- Kernel 2: xwg — glds-staged bf16 GEMM, counted-vmcnt ----------
__global__ __launch_bounds__(256, 4) void xwg_kernel(const short* __restrict__ xB,
                                                     const short* __restrict__ WT,
                                                     const float* __restrict__ d_is,
                                                     short* __restrict__ psT) {
    constexpr int NT = FIN / 32;  // 32
    __shared__ short As[2][4096];
    __shared__ short Bs[2][2048];

    const int tid = threadIdx.x;
    const int lin = blockIdx.x;
    const int swz = (lin & 7) * 64 + (lin >> 3);
    const int col0 = (swz & 7) * 64;
    const int row0 = (swz >> 3) * 128;

    const int lane = tid & 63;
    const int wv = tid >> 6;
    const int wr = wv >> 1, wc = wv & 1;
    const int l15 = lane & 15;
    const int kq = lane >> 4;
    const int xorv = (l15 & 12) << 2;

    int arow[2], acoff[2];
    #pragma unroll
    for (int i = 0; i < 2; ++i) {
        const int slot = i * 256 + tid;
        const int P = (slot << 4) ^ (slot & 48);
        arow[i] = P >> 6;
        acoff[i] = (P & 63) >> 1;
    }
    const short* Ab = xB + (size_t)row0 * FIN;
    const short* Bb = WT + (size_t)col0 * FIN;

    auto stage = [&](int buf, int k0) {
        #pragma unroll
        for (int i = 0; i < 2; ++i) {
            const short* src = Ab + (size_t)arow[i] * FIN + k0 + acoff[i];
            short* dst = &As[buf][(i * 256 + (tid & 192)) * 8];
            __builtin_amdgcn_global_load_lds(
                (const __attribute__((address_space(1))) unsigned int*)src,
                (__attribute__((address_space(3))) unsigned int*)dst, 16, 0, 0);
        }
        {
            const short* src = Bb + (size_t)arow[0] * FIN + k0 + acoff[0];
            short* dst = &Bs[buf][(tid & 192) * 8];
            __builtin_amdgcn_global_load_lds(
                (const __attribute__((address_space(1))) unsigned int*)src,
                (__attribute__((address_space(3))) unsigned int*)dst, 16, 0, 0);
        }
    };

    f32x4 acc[4][2] = {};
    auto compute = [&](int buf) {
        s16x8 af[4], bfr[2];
        #pragma unroll
        for (int m = 0; m < 4; ++m) {
            const int byteoff = ((wr * 64 + m * 16 + l15) * 64 + kq * 16) ^ xorv;
            af[m] = *reinterpret_cast<const s16x8*>(&As[buf][byteoff >> 1]);
        }
        #pragma unroll
        for (int n = 0; n < 2; ++n) {
            const int byteoff = ((wc * 32 + n * 16 + l15) * 64 + kq * 16) ^ xorv;
            bfr[n] = *reinterpret_cast<const s16x8*>(&Bs[buf][byteoff >> 1]);
        }
        #pragma unroll
        for (int m = 0; m < 4; ++m)
            #pragma unroll
            for (int n = 0; n < 2; ++n)
                acc[m][n] = __builtin_amdgcn_mfma_f32_16x16x32_bf16(af[m], bfr[n], acc[m][n], 0, 0, 0);
    };

    stage(0, 0);
    stage(1, 32);
    int cur = 0;
    #pragma unroll 1
    for (int t = 0; t < NT; ++t) {
        if (t < NT - 1) {
            asm volatile("s_waitcnt vmcnt(3)" ::: "memory");
        } else {
            asm volatile("s_waitcnt vmcnt(0)" ::: "memory");
        }
        __builtin_amdgcn_s_barrier();
        compute(cur);
        if (t + 2 < NT) {
            __builtin_amdgcn_s_barrier();
            stage(cur, (t + 2) * 32);
        }
        cur ^= 1;
    }

    #pragma unroll
    for (int m = 0; m < 4; ++m) {
        const int rbase = row0 + wr * 64 + m * 16 + kq * 4;
        float dr[4];
        #pragma unroll
        for (int j = 0; j < 4; ++j) dr[j] = d_is[rbase + j];
        #pragma unroll
        for (int n = 0; n < 2; ++n) {
            const int col = col0 + wc * 32 + n * 16 + l15;
            u16x4 pk;
            #pragma unroll
            for (int j = 0; j < 4; ++j) pk[j] = (unsigned short)f2bf(dr[j] * acc[m][n][j]);
            *reinterpret_cast<u16x4*>(&psT[(size_t)col * NN + rbase]) = pk;
        }
    }
}

// ---------- Kernel 3: prop3b — 256x256, A in LDS (glds), B global->regs, split-K=4 ----------
// A = adjB [8192][8192] bf16 via glds (swizzled, verified); B = psT bf16 read directly
// from global (8 MB, L2-resident). 512 thr, 8 waves (2x4, wave tile 128x64).
// LDS 64 KB: 2 buf x [2 kh][256 r][32 k] bf16. xwg-style wait-then-barrier schedule.
__global__ __launch_bounds__(512, 2) void prop3b_kernel(
    const short* __restrict__ adjB, const short* __restrict__ psT,
    short* __restrict__ Pb0, short* __restrict__ Pb1,
    short* __restrict__ Pb2, short* __restrict__ Pb3) {
    extern __shared__ short L[];  // 32768 shorts = 64 KB
    constexpr int NT = 32;        // 2048 / 64

    const int tid = threadIdx.x;
    const int lin = blockIdx.x;
    const int swz = (lin & 7) * 32 + (lin >> 3);   // bijective XCD chunking (256 = 8*32)
    // chunk of 32 shares ks (psT K-slice 1MB -> L2-hot per XCD): [ks(2)|row(5)|col(1)]
    const int col0 = (swz & 1) * 256;
    const int row0 = ((swz >> 1) & 31) * 256;
    const int ks = (swz >> 6) & 3;

    const int lane = tid & 63;
    const int wv = tid >> 6;
    const int wr = wv >> 2;        // 0..1: 128-row half
    const int wc = wv & 3;         // 0..3: 64-col quarter
    const int l15 = lane & 15;
    const int kq = lane >> 4;
    const int xorv = (l15 & 12) << 2;

    // A staging source indices (inverse-swizzled), per 16 KB kh-half
    int srow[2], scol[2];
    #pragma unroll
    for (int i = 0; i < 2; ++i) {
        const int slot = i * 512 + tid;
        const int P = (slot << 4) ^ (slot & 48);
        srow[i] = P >> 6;
        scol[i] = (P & 63) >> 1;
    }
    const size_t kbase = (size_t)ks * 2048;
    const short* Ab = adjB + (size_t)row0 * NN + kbase;
    // B base for this lane: row (col0 + wc*64 + l15), k offset kq*8
    const short* Bp = psT + (size_t)(col0 + wc * 64 + l15) * NN + kbase + kq * 8;

    auto stageA = [&](int buf, int kh, int t) {  // 2 vmem instr per call
        const int k0 = t * 64 + kh * 32;
        short* base = &L[buf * 16384 + kh * 8192];
        #pragma unroll
        for (int i = 0; i < 2; ++i) {
            const short* src = Ab + (size_t)srow[i] * NN + k0 + scol[i];
            short* dst = base + (i * 512 + (tid & 448)) * 8;
            __builtin_amdgcn_global_load_lds(
                (const __attribute__((address_space(1))) unsigned int*)src,
                (__attribute__((address_space(3))) unsigned int*)dst, 16, 0, 0);
        }
    };

    f32x4 acc[8][4] = {};

#define FENCE asm volatile("" ::: "memory")

#define LOADB(B, T)                                                                 \
    do {                                                                            \
        _Pragma("unroll")                                                           \
        for (int kh_ = 0; kh_ < 2; ++kh_)                                           \
            _Pragma("unroll")                                                       \
            for (int n_ = 0; n_ < 4; ++n_)                                          \
                B[kh_][n_] = *reinterpret_cast<const s16x8*>(                       \
                    Bp + (size_t)n_ * 16 * NN + (T) * 64 + kh_ * 32);               \
        FENCE;                                                                      \
    } while (0)

#define COMPUTE(BUF, B)                                                             \
    do {                                                                            \
        _Pragma("unroll")                                                           \
        for (int kh_ = 0; kh_ < 2; ++kh_) {                                         \
            const short* Ah_ = &L[(BUF) * 16384 + kh_ * 8192];                      \
            s16x8 af_[8];                                                           \
            _Pragma("unroll")                                                       \
            for (int m_ = 0; m_ < 8; ++m_) {                                        \
                const int ROW = wr * 128 + m_ * 16 + l15;                           \
                af_[m_] = *reinterpret_cast<const s16x8*>(                          \
                    &Ah_[((ROW * 64 + kq * 16) ^ xorv) >> 1]);                      \
            }                                                                       \
            __builtin_amdgcn_s_setprio(1);                                          \
            _Pragma("unroll")                                                       \
            for (int m_ = 0; m_ < 8; ++m_)                                          \
                _Pragma("unroll")                                                   \
                for (int n_ = 0; n_ < 4; ++n_)                                      \
                    acc[m_][n_] = __builtin_amdgcn_mfma_f32_16x16x32_bf16(          \
                        af_[m_], B[kh_][n_], acc[m_][n_], 0, 0, 0);                 \
            __builtin_amdgcn_s_setprio(0);                                          \
        }                                                                           \
    } while (0)

// One iteration: entry outstanding [A_T:4, B_T:8, A_{T+1}:4] (16) for T<NT-1,
// [A_T:4, B_T:8] (12) at T=NT-1. vmcnt(12)/(8) retires A_T; barrier; compute
// (compiler's B-reg wait vmcnt(4) retires B_T, keeps A_{T+1}); barrier; then
// issue B(T+1) BEFORE A(T+2) so in-order retirement never drains the prefetch.
#define ITER(T, BCUR, BNXT)                                                         \
    do {                                                                            \
        if ((T) < NT - 1) { asm volatile("s_waitcnt vmcnt(12)" ::: "memory"); }     \
        else              { asm volatile("s_waitcnt vmcnt(8)"  ::: "memory"); }     \
        __builtin_amdgcn_s_barrier();                                               \
        FENCE;                                                                      \
        COMPUTE((T) & 1, BCUR);                                                     \
        FENCE;                                                                      \
        __builtin_amdgcn_s_barrier();                                               \
        if ((T) + 1 < NT) LOADB(BNXT, (T) + 1);                                     \
        if ((T) + 2 < NT) { stageA((T) & 1, 0, (T) + 2);                            \
                            stageA((T) & 1, 1, (T) + 2); FENCE; }                   \
    } while (0)

    s16x8 bA[2][4], bB[2][4];

    // prologue: A0 (4), B0 (8), A1 (4)  -> outstanding 16
    stageA(0, 0, 0); stageA(0, 1, 0); FENCE;
    LOADB(bA, 0);
    stageA(1, 0, 1); stageA(1, 1, 1); FENCE;

    #pragma unroll 1
    for (int tt = 0; tt < NT; tt += 2) {
        ITER(tt, bA, bB);
        ITER(tt + 1, bB, bA);
    }

#undef ITER
#undef COMPUTE
#undef LOADB
#undef FENCE

    // epilogue: bf16 partials (C/D map: col = lane&15, row = kq*4 + j)
    short* Pt = (ks == 0) ? Pb0 : (ks == 1) ? Pb1 : (ks == 2) ? Pb2 : Pb3;
    #pragma unroll
    for (int mi = 0; mi < 8; ++mi) {
        const int rbase = row0 + wr * 128 + mi * 16 + kq * 4;
        #pragma unroll
        for (int n = 0; n < 4; ++n) {
            const int col = col0 + wc * 64 + n * 16 + l15;
            #pragma unroll
            for (int j = 0; j < 4; ++j)
                Pt[(size_t)(rbase + j) * FOUT + col] = f2bf(acc[mi][n][j]);
        }
    }
}

// ---------- Kernel 4: out = relu(d*(Pb0+Pb1+Pb2+Pb3 + psT^T) + b) ----------
__global__ __launch_bounds__(256) void ep4_kernel(
    const short* __restrict__ Pb0, const short* __restrict__ Pb1,
    const short* __restrict__ Pb2, const short* __restrict__ Pb3,
    float* __restrict__ out,
    const short* __restrict__ psT, const float* __restrict__ d_is,
    const float* __restrict__ bias) {
    const int col0 = blockIdx.x * 128;
    const int row0 = blockIdx.y * 32;
    const int t = threadIdx.x;
    const int c = col0 + (t & 31) * 4;
    const float4 bb = *reinterpret_cast<const float4*>(&bias[c]);
    #pragma unroll
    for (int it = 0; it < 4; ++it) {
        const int r = row0 + (t >> 5) + it * 8;
        const size_t idx = (size_t)r * FOUT + c;
        const u16x4 a = *reinterpret_cast<const u16x4*>(&Pb0[idx]);
        const u16x4 b4 = *reinterpret_cast<const u16x4*>(&Pb1[idx]);
        const u16x4 c4 = *reinterpret_cast<const u16x4*>(&Pb2[idx]);
        const u16x4 d4 = *reinterpret_cast<const u16x4*>(&Pb3[idx]);
        const float dr = d_is[r];
        float s[4], o4[4];
        #pragma unroll
        for (int j = 0; j < 4; ++j) s[j] = bf2f(psT[(size_t)(c + j) * NN + r]);
        const float bbv[4] = {bb.x, bb.y, bb.z, bb.w};
        #pragma unroll
        for (int j = 0; j < 4; ++j) {
            const float sum = ((bf2f((short)a[j]) + bf2f((short)b4[j])) +
                               (bf2f((short)c4[j]) + bf2f((short)d4[j]))) + s[j];
            o4[j] = fmaxf(dr * sum + bbv[j], 0.f);
        }
        float4 o = {o4[0], o4[1], o4[2], o4[3]};
        *reinterpret_cast<float4*>(&out[idx]) = o;
    }
}

// ---------- Fallback kernels (small-ws path) ----------
template<int KLEN, int MODE>
__global__ __launch_bounds__(256, 4) void gemm_kernel(
    const float* __restrict__ A, const short* __restrict__ B,
    const float* __restrict__ d_is,
    short* __restrict__ psT,
    float* __restrict__ P0, float* __restrict__ P1) {
    constexpr int KS = (MODE == 1) ? 2 : 1;
    constexpr int Ksub = KLEN / KS;
    constexpr int NT = Ksub / 32;
    constexpr int LDA = 40;
    __shared__ short As[2][128 * LDA];
    __shared__ short Bs[2][64 * LDA];

    const int tid = threadIdx.x;
    const int nchunk = gridDim.x >> 3;
    const int lin = blockIdx.x;
    const int swz = (lin & 7) * nchunk + (lin >> 3);
    const int col0 = (swz & 7) * 64;
    const int yp = (swz >> 3) & 63;
    const int ks = swz >> 9;
    const int row0 = yp * 128;
    const int kbase = ks * Ksub;

    const int lane = tid & 63;
    const int wv = tid >> 6;
    const int wr = wv >> 1, wc = wv & 1;
    const int l15 = lane & 15;
    const int koff = (lane >> 4) * 8;

    const int ar = tid >> 1, ak = (tid & 1) * 16;
    const float* Abase = A + (size_t)(row0 + ar) * KLEN + kbase + ak;
    const int br = tid >> 2, bk = (tid & 3) * 8;
    const short* Bbase = B + (size_t)(col0 + br) * KLEN + kbase + bk;

    float4 qa0, qa1, qa2, qa3;
    s16x8 qb;
    auto loadG = [&](int k0) {
        const float4* p = reinterpret_cast<const float4*>(Abase + k0);
        qa0 = p[0]; qa1 = p[1]; qa2 = p[2]; qa3 = p[3];
        qb = *reinterpret_cast<const s16x8*>(Bbase + k0);
    };
    auto writeL = [&](int buf) {
        const float a[16] = {qa0.x, qa0.y, qa0.z, qa0.w, qa1.x, qa1.y, qa1.z, qa1.w,
                             qa2.x, qa2.y, qa2.z, qa2.w, qa3.x, qa3.y, qa3.z, qa3.w};
        s16x8 v0, v1;
        #pragma unroll
        for (int e = 0; e < 8; ++e) { v0[e] = f2bf(a[e]); v1[e] = f2bf(a[8 + e]); }
        *reinterpret_cast<s16x8*>(&As[buf][ar * LDA + ak]) = v0;
        *reinterpret_cast<s16x8*>(&As[buf][ar * LDA + ak + 8]) = v1;
        *reinterpret_cast<s16x8*>(&Bs[buf][br * LDA + bk]) = qb;
    };

    f32x4 acc[4][2] = {};
    auto compute = [&](int buf) {
        s16x8 af[4], bfr[2];
        #pragma unroll
        for (int m = 0; m < 4; ++m)
            af[m] = *reinterpret_cast<const s16x8*>(&As[buf][(wr * 64 + m * 16 + l15) * LDA + koff]);
        #pragma unroll
        for (int n = 0; n < 2; ++n)
            bfr[n] = *reinterpret_cast<const s16x8*>(&Bs[buf][(wc * 32 + n * 16 + l15) * LDA + koff]);
        #pragma unroll
        for (int m = 0; m < 4; ++m)
            #pragma unroll
            for (int n = 0; n < 2; ++n)
                acc[m][n] = __builtin_amdgcn_mfma_f32_16x16x32_bf16(af[m], bfr[n], acc[m][n], 0, 0, 0);
    };

    loadG(0);
    writeL(0);
    __syncthreads();
    int cur = 0;
    for (int t = 0; t < NT; ++t) {
        if (t + 1 < NT) loadG((t + 1) * 32);
        compute(cur);
        if (t + 1 < NT) writeL(cur ^ 1);
        __syncthreads();
        cur ^= 1;
    }

    if (MODE == 0) {
        #pragma unroll
        for (int m = 0; m < 4; ++m) {
            const int rbase = row0 + wr * 64 + m * 16 + (lane >> 4) * 4;
            float dr[4];
            #pragma unroll
            for (int j = 0; j < 4; ++j) dr[j] = d_is[rbase + j];
            #pragma unroll
            for (int n = 0; n < 2; ++n) {
                const int col = col0 + wc * 32 + n * 16 + l15;
                u16x4 pk;
                #pragma unroll
                for (int j = 0; j < 4; ++j) pk[j] = (unsigned short)f2bf(dr[j] * acc[m][n][j]);
                *reinterpret_cast<u16x4*>(&psT[(size_t)col * NN + rbase]) = pk;
            }
        }
    } else {
        float* tgt = (ks == 0) ? P0 : P1;
        #pragma unroll
        for (int m = 0; m < 4; ++m) {
            const int rbase = row0 + wr * 64 + m * 16 + (lane >> 4) * 4;
            #pragma unroll
            for (int n = 0; n < 2; ++n) {
                const int col = col0 + wc * 32 + n * 16 + l15;
                f32x4 v = acc[m][n];
                if (ks == 0) {
                    const u16x4 sv = *reinterpret_cast<const u16x4*>(&psT[(size_t)col * NN + rbase]);
                    #pragma unroll
                    for (int j = 0; j < 4; ++j) v[j] += bf2f((short)sv[j]);
                }
                #pragma unroll
                for (int j = 0; j < 4; ++j)
                    tgt[(size_t)(rbase + j) * FOUT + col] = v[j];
            }
        }
    }
}

__global__ __launch_bounds__(256) void ep_kernel(const float* __restrict__ P0,
                                                 float* __restrict__ out,
                                                 const float* __restrict__ d_is,
                                                 const float* __restrict__ bias) {
    const size_t idx = ((size_t)blockIdx.x * 256 + threadIdx.x) * 4;
    const int row = (int)(idx >> 9);
    const int col = (int)(idx & 511);
    const float4 p0 = *reinterpret_cast<const float4*>(&P0[idx]);
    const float4 p1 = *reinterpret_cast<const float4*>(&out[idx]);
    const float4 bb = *reinterpret_cast<const float4*>(&bias[col]);
    const float dr = d_is[row];
    float4 o;
    o.x = fmaxf(dr * (p0.x + p1.x) + bb.x, 0.f);
    o.y = fmaxf(dr * (p0.y + p1.y) + bb.y, 0.f);
    o.z = fmaxf(dr * (p0.z + p1.z) + bb.z, 0.f);
    o.w = fmaxf(dr * (p0.w + p1.w) + bb.w, 0.f);
    *reinterpret_cast<float4*>(&out[idx]) = o;
}

extern "C" void kernel_launch(void* const* d_in, const int* in_sizes, int n_in,
                              void* d_out, int out_size, void* d_ws, size_t ws_size,
                              hipStream_t stream) {
    const float* x   = (const float*)d_in[0];
    const float* adj = (const float*)d_in[1];
    const float* W   = (const float*)d_in[2];
    const float* b   = (const float*)d_in[3];
    float* out = (float*)d_out;

    // Path A layout: psT | WT | xB | Pb0..Pb3 | dis | adjB
    const size_t NEED = (size_t)FOUT * NN * 2 + (size_t)FOUT * FIN * 2
                      + (size_t)NN * FIN * 2 + 4ull * NN * FOUT * 2
                      + NN * 4 + (size_t)NN * NN * 2;

    if (ws_size >= NEED) {
        short* psT = (short*)d_ws;
        short* WT  = psT + (size_t)FOUT * NN;
        short* xB  = WT + (size_t)FOUT * FIN;
        short* Pb0 = xB + (size_t)NN * FIN;
        short* Pb1 = Pb0 + (size_t)NN * FOUT;
        short* Pb2 = Pb1 + (size_t)NN * FOUT;
        short* Pb3 = Pb2 + (size_t)NN * FOUT;
        float* dis = (float*)(Pb3 + (size_t)NN * FOUT);
        short* adjB = (short*)(dis + NN);

        hipLaunchKernelGGL(prep_kernel, dim3(NN + 4096 + 128), dim3(256), 0, stream,
                           adj, adjB, dis, x, xB, W, WT);
        hipLaunchKernelGGL(xwg_kernel, dim3(512), dim3(256), 0, stream, xB, WT, dis, psT);
        hipLaunchKernelGGL(prop3b_kernel, dim3(256), dim3(512), 65536, stream,
                           adjB, psT, Pb0, Pb1, Pb2, Pb3);
        hipLaunchKernelGGL(ep4_kernel, dim3(4, 256), dim3(256), 0, stream,
                           Pb0, Pb1, Pb2, Pb3, out, psT, dis, b);
    } else {
        short* psT = (short*)d_ws;
        short* WT  = psT + (size_t)FOUT * NN;
        float* P0  = (float*)(WT + (size_t)FOUT * FIN);
        float* dis = P0 + (size_t)NN * FOUT;

        hipLaunchKernelGGL(rowsum_kernel, dim3(NN), dim3(256), 0, stream, adj, dis);
        hipLaunchKernelGGL(wt_kernel, dim3(8, 16), dim3(256), 0, stream, W, WT);
        hipLaunchKernelGGL((gemm_kernel<FIN, 0>), dim3(512), dim3(256), 0, stream,
                           x, WT, dis, psT, nullptr, nullptr);
        hipLaunchKernelGGL((gemm_kernel<NN, 1>), dim3(1024), dim3(256), 0, stream,
                           adj, psT, dis, psT, P0, out);
        hipLaunchKernelGGL(ep_kernel, dim3(NN * FOUT / 1024), dim3(256), 0, stream,
                           P0, out, dis, b);
    }
}

// Round 12
// 192.083 us; speedup vs baseline: 1.3727x; 1.3727x over previous
//
#include <hip/hip_runtime.h>
#include <stdint.h>

#define NN 8192
#define FIN 1024
#define FOUT 512

typedef __attribute__((ext_vector_type(4))) float f32x4;
typedef __attribute__((ext_vector_type(8))) short s16x8;
typedef __attribute__((ext_vector_type(4))) unsigned short u16x4;

__device__ __forceinline__ short f2bf(float f) {
    return __builtin_bit_cast(short, static_cast<__bf16>(f));
}
__device__ __forceinline__ float bf2f(short s) {
    return (float)__builtin_bit_cast(__bf16, s);
}

// ---------- Kernel 1 (path A): fused prep ----------
// blocks [0,8192): rowsum+cvt adj->adjB ; [8192,12288): x->xB ; [12288,12416): W->WT
__global__ __launch_bounds__(256) void prep_kernel(const float* __restrict__ adj,
                                                   short* __restrict__ adjB,
                                                   float* __restrict__ d_is,
                                                   const float* __restrict__ x,
                                                   short* __restrict__ xB,
                                                   const float* __restrict__ W,
                                                   short* __restrict__ WT) {
    __shared__ float red[4];
    __shared__ float T[64][68];
    const int b = blockIdx.x;
    const int t = threadIdx.x;
    if (b < NN) {
        const int row = b;
        const float4* a = reinterpret_cast<const float4*>(adj + (size_t)row * NN);
        u16x4* ob = reinterpret_cast<u16x4*>(adjB + (size_t)row * NN);
        float s = 0.f;
        #pragma unroll 2
        for (int j = t; j < NN / 4; j += 256) {
            float4 v = a[j];
            s += (v.x + v.y) + (v.z + v.w);
            u16x4 p;
            p[0] = (unsigned short)f2bf(v.x); p[1] = (unsigned short)f2bf(v.y);
            p[2] = (unsigned short)f2bf(v.z); p[3] = (unsigned short)f2bf(v.w);
            ob[j] = p;
        }
        #pragma unroll
        for (int off = 32; off > 0; off >>= 1) s += __shfl_down(s, off, 64);
        if ((t & 63) == 0) red[t >> 6] = s;
        __syncthreads();
        if (t == 0) {
            const float d = red[0] + red[1] + red[2] + red[3] + 1.0f;
            d_is[row] = 1.0f / sqrtf(d);
        }
    } else if (b < NN + 4096) {
        const size_t i = ((size_t)(b - NN) * 256 + t) * 8;
        const float4 v0 = *reinterpret_cast<const float4*>(&x[i]);
        const float4 v1 = *reinterpret_cast<const float4*>(&x[i + 4]);
        s16x8 o;
        o[0] = f2bf(v0.x); o[1] = f2bf(v0.y); o[2] = f2bf(v0.z); o[3] = f2bf(v0.w);
        o[4] = f2bf(v1.x); o[5] = f2bf(v1.y); o[6] = f2bf(v1.z); o[7] = f2bf(v1.w);
        *reinterpret_cast<s16x8*>(&xB[i]) = o;
    } else {
        const int bid = b - NN - 4096;
        const int wc = bid & 7;
        const int wk = bid >> 3;
        const int cc = (t & 15) * 4;
        #pragma unroll
        for (int i = 0; i < 4; ++i) {
            const int rr = (t >> 4) + i * 16;
            *reinterpret_cast<float4*>(&T[rr][cc]) =
                *reinterpret_cast<const float4*>(&W[(size_t)(wk * 64 + rr) * FOUT + wc * 64 + cc]);
        }
        __syncthreads();
        const int a = t >> 2;
        const int b0 = (t & 3) * 16;
        s16x8 v0, v1;
        #pragma unroll
        for (int e = 0; e < 8; ++e) { v0[e] = f2bf(T[b0 + e][a]); v1[e] = f2bf(T[b0 + 8 + e][a]); }
        short* dst = &WT[(size_t)(wc * 64 + a) * FIN + wk * 64 + b0];
        *reinterpret_cast<s16x8*>(dst) = v0;
        *reinterpret_cast<s16x8*>(dst + 8) = v1;
    }
}

// ---------- Kernel 1B (fallback): rowsum only ----------
__global__ __launch_bounds__(256) void rowsum_kernel(const float* __restrict__ adj,
                                                     float* __restrict__ d_is) {
    const int row = blockIdx.x;
    const float4* a = reinterpret_cast<const float4*>(adj + (size_t)row * NN);
    float s = 0.f;
    #pragma unroll 4
    for (int j = threadIdx.x; j < NN / 4; j += 256) {
        float4 v = a[j];
        s += (v.x + v.y) + (v.z + v.w);
    }
    #pragma unroll
    for (int off = 32; off > 0; off >>= 1) s += __shfl_down(s, off, 64);
    __shared__ float red[4];
    if ((threadIdx.x & 63) == 0) red[threadIdx.x >> 6] = s;
    __syncthreads();
    if (threadIdx.x == 0) {
        const float d = red[0] + red[1] + red[2] + red[3] + 1.0f;
        d_is[row] = 1.0f / sqrtf(d);
    }
}

// ---------- Kernel wt (fallback) ----------
__global__ __launch_bounds__(256) void wt_kernel(const float* __restrict__ W,
                                                 short* __restrict__ WT) {
    __shared__ float T[64][68];
    const int wc = blockIdx.x;
    const int wk = blockIdx.y;
    const int t = threadIdx.x;
    const int cc = (t & 15) * 4;
    #pragma unroll
    for (int i = 0; i < 4; ++i) {
        const int rr = (t >> 4) + i * 16;
        *reinterpret_cast<float4*>(&T[rr][cc]) =
            *reinterpret_cast<const float4*>(&W[(size_t)(wk * 64 + rr) * FOUT + wc * 64 + cc]);
    }
    __syncthreads();
    const int a = t >> 2;
    const int b0 = (t & 3) * 16;
    s16x8 v0, v1;
    #pragma unroll
    for (int e = 0; e < 8; ++e) { v0[e] = f2bf(T[b0 + e][a]); v1[e] = f2bf(T[b0 + 8 + e][a]); }
    short* dst = &WT[(size_t)(wc * 64 + a) * FIN + wk * 64 + b0];
    *reinterpret_cast<s16x8*>(dst) = v0;
    *reinterpret_cast<s16x8*>(dst + 8) = v1;
}

// ---------- Kernel 2: xwg — glds-staged bf16 GEMM, counted-vmcnt ----------
__global__ __launch_bounds__(256, 4) void xwg_kernel(const short* __restrict__ xB,
                                                     const short* __restrict__ WT,
                                                     const float* __restrict__ d_is,
                                                     short* __restrict__ psT) {
    constexpr int NT = FIN / 32;  // 32
    __shared__ short As[2][4096];
    __shared__ short Bs[2][2048];

    const int tid = threadIdx.x;
    const int lin = blockIdx.x;
    const int swz = (lin & 7) * 64 + (lin >> 3);
    const int col0 = (swz & 7) * 64;
    const int row0 = (swz >> 3) * 128;

    const int lane = tid & 63;
    const int wv = tid >> 6;
    const int wr = wv >> 1, wc = wv & 1;
    const int l15 = lane & 15;
    const int kq = lane >> 4;
    const int xorv = (l15 & 12) << 2;

    int arow[2], acoff[2];
    #pragma unroll
    for (int i = 0; i < 2; ++i) {
        const int slot = i * 256 + tid;
        const int P = (slot << 4) ^ (slot & 48);
        arow[i] = P >> 6;
        acoff[i] = (P & 63) >> 1;
    }
    const short* Ab = xB + (size_t)row0 * FIN;
    const short* Bb = WT + (size_t)col0 * FIN;

    auto stage = [&](int buf, int k0) {
        #pragma unroll
        for (int i = 0; i < 2; ++i) {
            const short* src = Ab + (size_t)arow[i] * FIN + k0 + acoff[i];
            short* dst = &As[buf][(i * 256 + (tid & 192)) * 8];
            __builtin_amdgcn_global_load_lds(
                (const __attribute__((address_space(1))) unsigned int*)src,
                (__attribute__((address_space(3))) unsigned int*)dst, 16, 0, 0);
        }
        {
            const short* src = Bb + (size_t)arow[0] * FIN + k0 + acoff[0];
            short* dst = &Bs[buf][(tid & 192) * 8];
            __builtin_amdgcn_global_load_lds(
                (const __attribute__((address_space(1))) unsigned int*)src,
                (__attribute__((address_space(3))) unsigned int*)dst, 16, 0, 0);
        }
    };

    f32x4 acc[4][2] = {};
    auto compute = [&](int buf) {
        s16x8 af[4], bfr[2];
        #pragma unroll
        for (int m = 0; m < 4; ++m) {
            const int byteoff = ((wr * 64 + m * 16 + l15) * 64 + kq * 16) ^ xorv;
            af[m] = *reinterpret_cast<const s16x8*>(&As[buf][byteoff >> 1]);
        }
        #pragma unroll
        for (int n = 0; n < 2; ++n) {
            const int byteoff = ((wc * 32 + n * 16 + l15) * 64 + kq * 16) ^ xorv;
            bfr[n] = *reinterpret_cast<const s16x8*>(&Bs[buf][byteoff >> 1]);
        }
        #pragma unroll
        for (int m = 0; m < 4; ++m)
            #pragma unroll
            for (int n = 0; n < 2; ++n)
                acc[m][n] = __builtin_amdgcn_mfma_f32_16x16x32_bf16(af[m], bfr[n], acc[m][n], 0, 0, 0);
    };

    stage(0, 0);
    stage(1, 32);
    int cur = 0;
    #pragma unroll 1
    for (int t = 0; t < NT; ++t) {
        if (t < NT - 1) {
            asm volatile("s_waitcnt vmcnt(3)" ::: "memory");
        } else {
            asm volatile("s_waitcnt vmcnt(0)" ::: "memory");
        }
        __builtin_amdgcn_s_barrier();
        compute(cur);
        if (t + 2 < NT) {
            __builtin_amdgcn_s_barrier();
            stage(cur, (t + 2) * 32);
        }
        cur ^= 1;
    }

    #pragma unroll
    for (int m = 0; m < 4; ++m) {
        const int rbase = row0 + wr * 64 + m * 16 + kq * 4;
        float dr[4];
        #pragma unroll
        for (int j = 0; j < 4; ++j) dr[j] = d_is[rbase + j];
        #pragma unroll
        for (int n = 0; n < 2; ++n) {
            const int col = col0 + wc * 32 + n * 16 + l15;
            u16x4 pk;
            #pragma unroll
            for (int j = 0; j < 4; ++j) pk[j] = (unsigned short)f2bf(dr[j] * acc[m][n][j]);
            *reinterpret_cast<u16x4*>(&psT[(size_t)col * NN + rbase]) = pk;
        }
    }
}

// ---------- Kernel 3: prop3 — 256x256 8-phase, counted vmcnt, split-K=4 ----------
// A = adjB [8192][8192] bf16, B = psT [512][8192] bf16. 512 thr, 8 waves (2x4).
// LDS 128 KB dynamic: 2 buf x { A[2 kh][256r][32k] | B[2 kh][256r][32k] }.
__global__ __launch_bounds__(512, 1) void prop3_kernel(
    const short* __restrict__ adjB, const short* __restrict__ psT,
    short* __restrict__ Pb0, short* __restrict__ Pb1,
    short* __restrict__ Pb2, short* __restrict__ Pb3) {
    extern __shared__ short L[];  // 65536 shorts = 128 KB

    const int tid = threadIdx.x;
    const int lin = blockIdx.x;
    const int swz = (lin & 7) * 32 + (lin >> 3);   // bijective XCD chunking (256 = 8*32)
    const int col0 = (swz & 1) * 256;
    const int ks = (swz >> 1) & 3;
    const int row0 = (swz >> 3) * 256;

    const int lane = tid & 63;
    const int wv = tid >> 6;        // 0..7
    const int wr = wv >> 2;         // 0..1: row half (128 rows)
    const int wc = wv & 3;          // 0..3: col quarter (64 cols)
    const int l15 = lane & 15;
    const int kq = lane >> 4;
    const int xorv = (l15 & 12) << 2;

    // staging source indices (inverse-swizzled): slot = i*512 + tid over a 16 KB half
    int srow[2], scol[2];
    #pragma unroll
    for (int i = 0; i < 2; ++i) {
        const int slot = i * 512 + tid;
        const int P = (slot << 4) ^ (slot & 48);
        srow[i] = P >> 6;          // 0..255
        scol[i] = (P & 63) >> 1;   // 0..31
    }
    const size_t kbase = (size_t)ks * 2048;
    const short* Ab = adjB + (size_t)row0 * NN + kbase;
    const short* Bb = psT + (size_t)col0 * NN + kbase;

    // stage one half-tile (16 KB): op 0=A,1=B; k-half kh of tile t into buffer buf
    auto stageH = [&](int buf, int op, int kh, int t) {
        const short* s0 = op ? Bb : Ab;
        const int k0 = t * 64 + kh * 32;
        short* base = &L[buf * 32768 + op * 16384 + kh * 8192];
        #pragma unroll
        for (int i = 0; i < 2; ++i) {
            const short* src = s0 + (size_t)srow[i] * NN + k0 + scol[i];
            short* dst = base + (i * 512 + (tid & 448)) * 8;
            __builtin_amdgcn_global_load_lds(
                (const __attribute__((address_space(1))) unsigned int*)src,
                (__attribute__((address_space(3))) unsigned int*)dst, 16, 0, 0);
        }
    };

    f32x4 acc[8][4] = {};

#define LDFRAG(BASE, ROW) \
    (*reinterpret_cast<const s16x8*>(&(BASE)[((((ROW) * 64 + kq * 16)) ^ xorv) >> 1]))

#define PHASE(BUF, KH, QM, STAGE_STMT, VM_STMT)                                     \
    do {                                                                            \
        const short* Ah_ = &L[(BUF) * 32768 + (KH) * 8192];                         \
        const short* Bh_ = &L[(BUF) * 32768 + 16384 + (KH) * 8192];                 \
        s16x8 af_[4], bg_[4];                                                       \
        _Pragma("unroll")                                                           \
        for (int m = 0; m < 4; ++m)                                                 \
            af_[m] = LDFRAG(Ah_, wr * 128 + (QM) * 64 + m * 16 + l15);              \
        _Pragma("unroll")                                                           \
        for (int n = 0; n < 4; ++n)                                                 \
            bg_[n] = LDFRAG(Bh_, wc * 64 + n * 16 + l15);                           \
        STAGE_STMT;                                                                 \
        asm volatile("" ::: "memory");                                              \
        __builtin_amdgcn_s_barrier();                                               \
        __builtin_amdgcn_s_setprio(1);                                              \
        _Pragma("unroll")                                                           \
        for (int m = 0; m < 4; ++m)                                                 \
            _Pragma("unroll")                                                       \
            for (int n = 0; n < 4; ++n)                                             \
                acc[(QM) * 4 + m][n] = __builtin_amdgcn_mfma_f32_16x16x32_bf16(     \
                    af_[m], bg_[n], acc[(QM) * 4 + m][n], 0, 0, 0);                 \
        __builtin_amdgcn_s_setprio(0);                                              \
        VM_STMT;                                                                    \
        asm volatile("" ::: "memory");                                              \
        __builtin_amdgcn_s_barrier();                                               \
    } while (0)

#define VM4 asm volatile("s_waitcnt vmcnt(4)" ::: "memory")
#define VM0 asm volatile("s_waitcnt vmcnt(0)" ::: "memory")

    // prologue: tile0 all 4 halves + tile1 {A0,B0}  (12 vmem instr/wave)
    stageH(0, 0, 0, 0); stageH(0, 1, 0, 0);
    stageH(0, 0, 1, 0); stageH(0, 1, 1, 0);
    stageH(1, 0, 0, 1); stageH(1, 1, 0, 1);
    asm volatile("s_waitcnt vmcnt(8)" ::: "memory");   // tile0 {A0,B0} landed
    __builtin_amdgcn_s_barrier();

    // t = 0 (buf 0): t1 {A0,B0} pre-staged; issue t1 {A1,B1} at phases 2,3
    PHASE(0, 0, 0, (void)0,             (void)0);
    PHASE(0, 0, 1, (void)0,             VM4);
    PHASE(0, 1, 0, stageH(1, 0, 1, 1),  (void)0);
    PHASE(0, 1, 1, stageH(1, 1, 1, 1),  VM4);

    // steady t = 1..30
    #pragma unroll 1
    for (int t = 1; t <= 30; ++t) {
        const int buf = t & 1, nb = buf ^ 1, tn = t + 1;
        PHASE(buf, 0, 0, stageH(nb, 0, 0, tn), (void)0);
        PHASE(buf, 0, 1, stageH(nb, 1, 0, tn), VM4);
        PHASE(buf, 1, 0, stageH(nb, 0, 1, tn), (void)0);
        PHASE(buf, 1, 1, stageH(nb, 1, 1, tn), VM4);
    }

    // t = 31 (buf 1): no more staging
    PHASE(1, 0, 0, (void)0, (void)0);
    PHASE(1, 0, 1, (void)0, VM0);
    PHASE(1, 1, 0, (void)0, (void)0);
    PHASE(1, 1, 1, (void)0, (void)0);

    // epilogue: bf16 partials (C/D map: col = lane&15, row = kq*4 + j)
    {
        short* Pt = (ks == 0) ? Pb0 : (ks == 1) ? Pb1 : (ks == 2) ? Pb2 : Pb3;
        #pragma unroll
        for (int mi = 0; mi < 8; ++mi) {
            const int rbase = row0 + wr * 128 + mi * 16 + kq * 4;
            #pragma unroll
            for (int n = 0; n < 4; ++n) {
                const int col = col0 + wc * 64 + n * 16 + l15;
                #pragma unroll
                for (int j = 0; j < 4; ++j)
                    Pt[(size_t)(rbase + j) * FOUT + col] = f2bf(acc[mi][n][j]);
            }
        }
    }
#undef PHASE
#undef LDFRAG
#undef VM4
#undef VM0
}

// ---------- Kernel 4: out = relu(d*(Pb0+Pb1+Pb2+Pb3 + psT^T) + b) ----------
__global__ __launch_bounds__(256) void ep4_kernel(
    const short* __restrict__ Pb0, const short* __restrict__ Pb1,
    const short* __restrict__ Pb2, const short* __restrict__ Pb3,
    float* __restrict__ out,
    const short* __restrict__ psT, const float* __restrict__ d_is,
    const float* __restrict__ bias) {
    const int col0 = blockIdx.x * 128;
    const int row0 = blockIdx.y * 32;
    const int t = threadIdx.x;
    const int c = col0 + (t & 31) * 4;
    const float4 bb = *reinterpret_cast<const float4*>(&bias[c]);
    #pragma unroll
    for (int it = 0; it < 4; ++it) {
        const int r = row0 + (t >> 5) + it * 8;
        const size_t idx = (size_t)r * FOUT + c;
        const u16x4 a = *reinterpret_cast<const u16x4*>(&Pb0[idx]);
        const u16x4 b4 = *reinterpret_cast<const u16x4*>(&Pb1[idx]);
        const u16x4 c4 = *reinterpret_cast<const u16x4*>(&Pb2[idx]);
        const u16x4 d4 = *reinterpret_cast<const u16x4*>(&Pb3[idx]);
        const float dr = d_is[r];
        float s[4], o4[4];
        #pragma unroll
        for (int j = 0; j < 4; ++j) s[j] = bf2f(psT[(size_t)(c + j) * NN + r]);
        const float bbv[4] = {bb.x, bb.y, bb.z, bb.w};
        #pragma unroll
        for (int j = 0; j < 4; ++j) {
            const float sum = ((bf2f((short)a[j]) + bf2f((short)b4[j])) +
                               (bf2f((short)c4[j]) + bf2f((short)d4[j]))) + s[j];
            o4[j] = fmaxf(dr * sum + bbv[j], 0.f);
        }
        float4 o = {o4[0], o4[1], o4[2], o4[3]};
        *reinterpret_cast<float4*>(&out[idx]) = o;
    }
}

// ---------- Fallback kernels (small-ws path) ----------
template<int KLEN, int MODE>
__global__ __launch_bounds__(256, 4) void gemm_kernel(
    const float* __restrict__ A, const short* __restrict__ B,
    const float* __restrict__ d_is,
    short* __restrict__ psT,
    float* __restrict__ P0, float* __restrict__ P1) {
    constexpr int KS = (MODE == 1) ? 2 : 1;
    constexpr int Ksub = KLEN / KS;
    constexpr int NT = Ksub / 32;
    constexpr int LDA = 40;
    __shared__ short As[2][128 * LDA];
    __shared__ short Bs[2][64 * LDA];

    const int tid = threadIdx.x;
    const int nchunk = gridDim.x >> 3;
    const int lin = blockIdx.x;
    const int swz = (lin & 7) * nchunk + (lin >> 3);
    const int col0 = (swz & 7) * 64;
    const int yp = (swz >> 3) & 63;
    const int ks = swz >> 9;
    const int row0 = yp * 128;
    const int kbase = ks * Ksub;

    const int lane = tid & 63;
    const int wv = tid >> 6;
    const int wr = wv >> 1, wc = wv & 1;
    const int l15 = lane & 15;
    const int koff = (lane >> 4) * 8;

    const int ar = tid >> 1, ak = (tid & 1) * 16;
    const float* Abase = A + (size_t)(row0 + ar) * KLEN + kbase + ak;
    const int br = tid >> 2, bk = (tid & 3) * 8;
    const short* Bbase = B + (size_t)(col0 + br) * KLEN + kbase + bk;

    float4 qa0, qa1, qa2, qa3;
    s16x8 qb;
    auto loadG = [&](int k0) {
        const float4* p = reinterpret_cast<const float4*>(Abase + k0);
        qa0 = p[0]; qa1 = p[1]; qa2 = p[2]; qa3 = p[3];
        qb = *reinterpret_cast<const s16x8*>(Bbase + k0);
    };
    auto writeL = [&](int buf) {
        const float a[16] = {qa0.x, qa0.y, qa0.z, qa0.w, qa1.x, qa1.y, qa1.z, qa1.w,
                             qa2.x, qa2.y, qa2.z, qa2.w, qa3.x, qa3.y, qa3.z, qa3.w};
        s16x8 v0, v1;
        #pragma unroll
        for (int e = 0; e < 8; ++e) { v0[e] = f2bf(a[e]); v1[e] = f2bf(a[8 + e]); }
        *reinterpret_cast<s16x8*>(&As[buf][ar * LDA + ak]) = v0;
        *reinterpret_cast<s16x8*>(&As[buf][ar * LDA + ak + 8]) = v1;
        *reinterpret_cast<s16x8*>(&Bs[buf][br * LDA + bk]) = qb;
    };

    f32x4 acc[4][2] = {};
    auto compute = [&](int buf) {
        s16x8 af[4], bfr[2];
        #pragma unroll
        for (int m = 0; m < 4; ++m)
            af[m] = *reinterpret_cast<const s16x8*>(&As[buf][(wr * 64 + m * 16 + l15) * LDA + koff]);
        #pragma unroll
        for (int n = 0; n < 2; ++n)
            bfr[n] = *reinterpret_cast<const s16x8*>(&Bs[buf][(wc * 32 + n * 16 + l15) * LDA + koff]);
        #pragma unroll
        for (int m = 0; m < 4; ++m)
            #pragma unroll
            for (int n = 0; n < 2; ++n)
                acc[m][n] = __builtin_amdgcn_mfma_f32_16x16x32_bf16(af[m], bfr[n], acc[m][n], 0, 0, 0);
    };

    loadG(0);
    writeL(0);
    __syncthreads();
    int cur = 0;
    for (int t = 0; t < NT; ++t) {
        if (t + 1 < NT) loadG((t + 1) * 32);
        compute(cur);
        if (t + 1 < NT) writeL(cur ^ 1);
        __syncthreads();
        cur ^= 1;
    }

    if (MODE == 0) {
        #pragma unroll
        for (int m = 0; m < 4; ++m) {
            const int rbase = row0 + wr * 64 + m * 16 + (lane >> 4) * 4;
            float dr[4];
            #pragma unroll
            for (int j = 0; j < 4; ++j) dr[j] = d_is[rbase + j];
            #pragma unroll
            for (int n = 0; n < 2; ++n) {
                const int col = col0 + wc * 32 + n * 16 + l15;
                u16x4 pk;
                #pragma unroll
                for (int j = 0; j < 4; ++j) pk[j] = (unsigned short)f2bf(dr[j] * acc[m][n][j]);
                *reinterpret_cast<u16x4*>(&psT[(size_t)col * NN + rbase]) = pk;
            }
        }
    } else {
        float* tgt = (ks == 0) ? P0 : P1;
        #pragma unroll
        for (int m = 0; m < 4; ++m) {
            const int rbase = row0 + wr * 64 + m * 16 + (lane >> 4) * 4;
            #pragma unroll
            for (int n = 0; n < 2; ++n) {
                const int col = col0 + wc * 32 + n * 16 + l15;
                f32x4 v = acc[m][n];
                if (ks == 0) {
                    const u16x4 sv = *reinterpret_cast<const u16x4*>(&psT[(size_t)col * NN + rbase]);
                    #pragma unroll
                    for (int j = 0; j < 4; ++j) v[j] += bf2f((short)sv[j]);
                }
                #pragma unroll
                for (int j = 0; j < 4; ++j)
                    tgt[(size_t)(rbase + j) * FOUT + col] = v[j];
            }
        }
    }
}

__global__ __launch_bounds__(256) void ep_kernel(const float* __restrict__ P0,
                                                 float* __restrict__ out,
                                                 const float* __restrict__ d_is,
                                                 const float* __restrict__ bias) {
    const size_t idx = ((size_t)blockIdx.x * 256 + threadIdx.x) * 4;
    const int row = (int)(idx >> 9);
    const int col = (int)(idx & 511);
    const float4 p0 = *reinterpret_cast<const float4*>(&P0[idx]);
    const float4 p1 = *reinterpret_cast<const float4*>(&out[idx]);
    const float4 bb = *reinterpret_cast<const float4*>(&bias[col]);
    const float dr = d_is[row];
    float4 o;
    o.x = fmaxf(dr * (p0.x + p1.x) + bb.x, 0.f);
    o.y = fmaxf(dr * (p0.y + p1.y) + bb.y, 0.f);
    o.z = fmaxf(dr * (p0.z + p1.z) + bb.z, 0.f);
    o.w = fmaxf(dr * (p0.w + p1.w) + bb.w, 0.f);
    *reinterpret_cast<float4*>(&out[idx]) = o;
}

extern "C" void kernel_launch(void* const* d_in, const int* in_sizes, int n_in,
                              void* d_out, int out_size, void* d_ws, size_t ws_size,
                              hipStream_t stream) {
    const float* x   = (const float*)d_in[0];
    const float* adj = (const float*)d_in[1];
    const float* W   = (const float*)d_in[2];
    const float* b   = (const float*)d_in[3];
    float* out = (float*)d_out;

    // Path A layout: psT | WT | xB | Pb0..Pb3 | dis | adjB
    const size_t NEED = (size_t)FOUT * NN * 2 + (size_t)FOUT * FIN * 2
                      + (size_t)NN * FIN * 2 + 4ull * NN * FOUT * 2
                      + NN * 4 + (size_t)NN * NN * 2;

    if (ws_size >= NEED) {
        short* psT = (short*)d_ws;
        short* WT  = psT + (size_t)FOUT * NN;
        short* xB  = WT + (size_t)FOUT * FIN;
        short* Pb0 = xB + (size_t)NN * FIN;
        short* Pb1 = Pb0 + (size_t)NN * FOUT;
        short* Pb2 = Pb1 + (size_t)NN * FOUT;
        short* Pb3 = Pb2 + (size_t)NN * FOUT;
        float* dis = (float*)(Pb3 + (size_t)NN * FOUT);
        short* adjB = (short*)(dis + NN);

        hipLaunchKernelGGL(prep_kernel, dim3(NN + 4096 + 128), dim3(256), 0, stream,
                           adj, adjB, dis, x, xB, W, WT);
        hipLaunchKernelGGL(xwg_kernel, dim3(512), dim3(256), 0, stream, xB, WT, dis, psT);
        hipLaunchKernelGGL(prop3_kernel, dim3(256), dim3(512), 131072, stream,
                           adjB, psT, Pb0, Pb1, Pb2, Pb3);
        hipLaunchKernelGGL(ep4_kernel, dim3(4, 256), dim3(256), 0, stream,
                           Pb0, Pb1, Pb2, Pb3, out, psT, dis, b);
    } else {
        short* psT = (short*)d_ws;
        short* WT  = psT + (size_t)FOUT * NN;
        float* P0  = (float*)(WT + (size_t)FOUT * FIN);
        float* dis = P0 + (size_t)NN * FOUT;

        hipLaunchKernelGGL(rowsum_kernel, dim3(NN), dim3(256), 0, stream, adj, dis);
        hipLaunchKernelGGL(wt_kernel, dim3(8, 16), dim3(256), 0, stream, W, WT);
        hipLaunchKernelGGL((gemm_kernel<FIN, 0>), dim3(512), dim3(256), 0, stream,
                           x, WT, dis, psT, nullptr, nullptr);
        hipLaunchKernelGGL((gemm_kernel<NN, 1>), dim3(1024), dim3(256), 0, stream,
                           adj, psT, dis, psT, P0, out);
        hipLaunchKernelGGL(ep_kernel, dim3(NN * FOUT / 1024), dim3(256), 0, stream,
                           P0, out, dis, b);
    }
}